// Round 2
// baseline (222.796 us; speedup 1.0000x reference)
//
#include <hip/hip_runtime.h>
#include <stdint.h>

#define TPB 256
#define FDIM 512
#define HD 32
#define AD 8

__device__ __forceinline__ uint32_t rotl32(uint32_t x, int r) {
  return (x << r) | (x >> (32 - r));
}

// Threefry-2x32 with key (0, 42) == jax.random.key(42); 20 rounds, matches
// jax/_src/prng.py exactly.
__device__ __forceinline__ void tf2x32_key42(uint32_t& x0, uint32_t& x1) {
  const uint32_t ks0 = 0u, ks1 = 42u, ks2 = 0x1BD11BDAu ^ 0u ^ 42u;
  x0 += ks0; x1 += ks1;
#define TFR(r) { x0 += x1; x1 = rotl32(x1, (r)); x1 ^= x0; }
  TFR(13) TFR(15) TFR(26) TFR(6)
  x0 += ks1; x1 += ks2 + 1u;
  TFR(17) TFR(29) TFR(16) TFR(24)
  x0 += ks2; x1 += ks0 + 2u;
  TFR(13) TFR(15) TFR(26) TFR(6)
  x0 += ks0; x1 += ks1 + 3u;
  TFR(17) TFR(29) TFR(16) TFR(24)
  x0 += ks1; x1 += ks2 + 4u;
  TFR(13) TFR(15) TFR(26) TFR(6)
  x0 += ks2; x1 += ks0 + 5u;
#undef TFR
}

// jax.random.normal f32: u in [0,1) from top 23 bits; v = max(lo, u*2+lo),
// lo = nextafter(-1,0); z = sqrt(2)*erfinv(v) with XLA ErfInv32 (Giles) poly.
__device__ __forceinline__ float jax_normal_from_bits(uint32_t bits) {
  float u = __uint_as_float((bits >> 9) | 0x3f800000u) - 1.0f;
  const float lo = -0.99999994f;           // nextafter(-1, 0)
  float v = fmaxf(lo, fmaf(u, 2.0f, lo));  // (hi - lo) rounds to exactly 2.0f
  float w = -log1pf(-v * v);
  float p;
  if (w < 5.0f) {
    w -= 2.5f;
    p = 2.81022636e-08f;
    p = fmaf(p, w, 3.43273939e-07f);
    p = fmaf(p, w, -3.5233877e-06f);
    p = fmaf(p, w, -4.39150654e-06f);
    p = fmaf(p, w, 0.00021858087f);
    p = fmaf(p, w, -0.00125372503f);
    p = fmaf(p, w, -0.00417768164f);
    p = fmaf(p, w, 0.246640727f);
    p = fmaf(p, w, 1.50140941f);
  } else {
    w = sqrtf(w) - 3.0f;
    p = -0.000200214257f;
    p = fmaf(p, w, 0.000100950558f);
    p = fmaf(p, w, 0.00134934322f);
    p = fmaf(p, w, -0.00367342844f);
    p = fmaf(p, w, 0.00573950773f);
    p = fmaf(p, w, -0.0076224613f);
    p = fmaf(p, w, 0.00943887047f);
    p = fmaf(p, w, 1.00167406f);
    p = fmaf(p, w, 2.83297682f);
  }
  return 1.41421356f * (p * v);
}

// One thread = one row, fully fused: MLP(512->32->32), heads, diagonal NAF
// closed form, Threefry sampling (partitionable scheme: counter=(0,e),
// bits = out0 ^ out1). W1 staged through 32KB LDS in two K-halves.
__global__ __launch_bounds__(TPB, 4) void naf_fused(
    const float* __restrict__ X, const float* __restrict__ RL,
    const float* __restrict__ act,
    const float* __restrict__ W1, const float* __restrict__ b1,
    const float* __restrict__ W2, const float* __restrict__ b2,
    const float* __restrict__ Wv, const float* __restrict__ bv,
    const float* __restrict__ Wmu, const float* __restrict__ bmu,
    const float* __restrict__ WL, const float* __restrict__ bL,
    float* __restrict__ out, int N) {
  __shared__ float sW1[(FDIM / 2) * HD];  // 32 KB, one K-half at a time
  __shared__ float sW2[HD * HD];          // 4 KB
  __shared__ float sWmu[HD * AD];         // [k][a]
  __shared__ float sWLd[HD * AD];         // diag columns of WL, [k][a]
  __shared__ float sWv[HD];
  __shared__ float sb1[HD], sb2[HD], sbmu[AD], sbLd[AD];
  __shared__ float sbv;

  const int tid = threadIdx.x;

  // ---- stage small weights once ----
  for (int i = tid; i < HD * HD; i += TPB) sW2[i] = W2[i];
  for (int i = tid; i < HD * AD; i += TPB) {
    sWmu[i] = Wmu[i];
    int k = i >> 3, a = i & 7;
    sWLd[i] = WL[k * 36 + ((a * a + 3 * a) >> 1)];  // tril diag index a(a+3)/2
  }
  if (tid < HD) { sWv[tid] = Wv[tid]; sb1[tid] = b1[tid]; sb2[tid] = b2[tid]; }
  if (tid < AD) { sbmu[tid] = bmu[tid]; sbLd[tid] = bL[(tid * tid + 3 * tid) >> 1]; }
  if (tid == 0) sbv = bv[0];

  const int row = blockIdx.x * TPB + tid;
  const bool active = row < N;
  const float4* xr =
      reinterpret_cast<const float4*>(X) + (size_t)(active ? row : 0) * (FDIM / 4);

  float acc[HD];
#pragma unroll
  for (int c = 0; c < HD; ++c) acc[c] = 0.0f;

  // ---- layer 1: X[row,:] @ W1, K split into two 256-wide LDS-staged halves ----
  for (int half = 0; half < 2; ++half) {
    __syncthreads();  // previous-half consumers done (also orders small staging)
    {
      const float4* W1v = reinterpret_cast<const float4*>(W1);
      float4* sW1v = reinterpret_cast<float4*>(sW1);
      for (int i = tid; i < (FDIM / 2) * HD / 4; i += TPB)
        sW1v[i] = W1v[half * ((FDIM / 2) * HD / 4) + i];
    }
    __syncthreads();
    if (active) {
      const float4* w1v = reinterpret_cast<const float4*>(sW1);
#pragma unroll 2
      for (int kk = 0; kk < FDIM / 8; ++kk) {  // 64 float4 of x per half
        float4 xv = xr[half * (FDIM / 8) + kk];
        float xs[4] = {xv.x, xv.y, xv.z, xv.w};
#pragma unroll
        for (int j = 0; j < 4; ++j) {
          const int base = (kk * 4 + j) * (HD / 4);
#pragma unroll
          for (int q = 0; q < HD / 4; ++q) {
            float4 wv = w1v[base + q];  // wave-uniform address -> LDS broadcast
            acc[4 * q + 0] = fmaf(xs[j], wv.x, acc[4 * q + 0]);
            acc[4 * q + 1] = fmaf(xs[j], wv.y, acc[4 * q + 1]);
            acc[4 * q + 2] = fmaf(xs[j], wv.z, acc[4 * q + 2]);
            acc[4 * q + 3] = fmaf(xs[j], wv.w, acc[4 * q + 3]);
          }
        }
      }
    }
  }
  if (!active) return;  // no __syncthreads below this point

  float h1[HD];
#pragma unroll
  for (int c = 0; c < HD; ++c) h1[c] = fmaxf(acc[c] + sb1[c], 0.0f);

  // ---- layer 2: 32x32 ----
#pragma unroll
  for (int c = 0; c < HD; ++c) acc[c] = 0.0f;
  {
    const float4* w2v = reinterpret_cast<const float4*>(sW2);
#pragma unroll 4
    for (int k = 0; k < HD; ++k) {
      const float hk = h1[k];
#pragma unroll
      for (int q = 0; q < HD / 4; ++q) {
        float4 wv = w2v[k * (HD / 4) + q];
        acc[4 * q + 0] = fmaf(hk, wv.x, acc[4 * q + 0]);
        acc[4 * q + 1] = fmaf(hk, wv.y, acc[4 * q + 1]);
        acc[4 * q + 2] = fmaf(hk, wv.z, acc[4 * q + 2]);
        acc[4 * q + 3] = fmaf(hk, wv.w, acc[4 * q + 3]);
      }
    }
  }
  float h2[HD];
#pragma unroll
  for (int c = 0; c < HD; ++c) h2[c] = fmaxf(acc[c] + sb2[c], 0.0f);

  // ---- heads: value, mu (8), L-diagonal (8) ----
  float vacc = 0.0f;
  float mua[AD], dva[AD];
#pragma unroll
  for (int a = 0; a < AD; ++a) { mua[a] = 0.0f; dva[a] = 0.0f; }
#pragma unroll 4
  for (int k = 0; k < HD; ++k) {
    const float hk = h2[k];
    vacc = fmaf(hk, sWv[k], vacc);
#pragma unroll
    for (int a = 0; a < AD; ++a) {
      mua[a] = fmaf(hk, sWmu[k * AD + a], mua[a]);
      dva[a] = fmaf(hk, sWLd[k * AD + a], dva[a]);
    }
  }
  vacc += sbv;

  // ---- diagonal NAF closed form + Threefry sampling (partitionable) ----
  const float actn = act[row];
  const float rl = RL[row];
  float adv = 0.0f;
  float smp[AD];
#pragma unroll
  for (int a = 0; a < AD; ++a) {
    const float mu = tanhf(mua[a] + sbmu[a]);
    const float dd = tanhf(dva[a] + sbLd[a]);
    const float ld = expf(dd);     // L diagonal; P_aa = ld^2; Lc_aa = 1/ld
    const float am = actn - mu;
    adv = fmaf(am * am, ld * ld, adv);
    // jax_threefry_partitionable: counter = 64-bit element index e ->
    // (x0, x1) = (hi32(e), lo32(e)) = (0, e); 32-bit bits = out0 ^ out1.
    const uint32_t e = (uint32_t)row * AD + (uint32_t)a;
    uint32_t x0 = 0u;
    uint32_t x1 = e;
    tf2x32_key42(x0, x1);
    const float z = jax_normal_from_bits(x0 ^ x1);
    float s = fmaf(z, 1.0f / ld, mu);
    s = fminf(fmaxf(s, -1.0f), 1.0f) * rl;
    smp[a] = s;
  }
  const float q = fmaf(-0.5f, adv, vacc);

  float4* so = reinterpret_cast<float4*>(out) + (size_t)row * 2;
  so[0] = make_float4(smp[0], smp[1], smp[2], smp[3]);
  so[1] = make_float4(smp[4], smp[5], smp[6], smp[7]);
  out[(size_t)N * AD + row] = q;                  // Q
  out[(size_t)N * AD + (size_t)N + row] = vacc;   // value
}

extern "C" void kernel_launch(void* const* d_in, const int* in_sizes, int n_in,
                              void* d_out, int out_size, void* d_ws, size_t ws_size,
                              hipStream_t stream) {
  const float* X   = (const float*)d_in[0];
  const float* RL  = (const float*)d_in[1];
  const float* act = (const float*)d_in[2];
  const float* W1  = (const float*)d_in[3];
  const float* b1  = (const float*)d_in[4];
  const float* W2  = (const float*)d_in[5];
  const float* b2  = (const float*)d_in[6];
  const float* Wv  = (const float*)d_in[7];
  const float* bv  = (const float*)d_in[8];
  const float* Wmu = (const float*)d_in[9];
  const float* bmu = (const float*)d_in[10];
  const float* WL  = (const float*)d_in[11];
  const float* bL  = (const float*)d_in[12];
  const int N = in_sizes[1];  // RL_indice length
  const int blocks = (N + TPB - 1) / TPB;
  hipLaunchKernelGGL(naf_fused, dim3(blocks), dim3(TPB), 0, stream,
                     X, RL, act, W1, b1, W2, b2, Wv, bv, Wmu, bmu, WL, bL,
                     (float*)d_out, N);
}

// Round 3
// 203.985 us; speedup vs baseline: 1.0922x; 1.0922x over previous
//
#include <hip/hip_runtime.h>
#include <stdint.h>

#define TPB 256
#define FDIM 512
#define HD 32
#define AD 8
#define KT 32              // K-tile width (cols of X per stage)
#define NTILE (FDIM / KT)  // 16
#define XPITCH 36          // 32 + 4 pad floats: keeps float4 alignment, breaks bank stride

__device__ __forceinline__ uint32_t rotl32(uint32_t x, int r) {
  return (x << r) | (x >> (32 - r));
}

// Threefry-2x32 with key (0, 42) == jax.random.key(42); 20 rounds.
__device__ __forceinline__ void tf2x32_key42(uint32_t& x0, uint32_t& x1) {
  const uint32_t ks0 = 0u, ks1 = 42u, ks2 = 0x1BD11BDAu ^ 0u ^ 42u;
  x0 += ks0; x1 += ks1;
#define TFR(r) { x0 += x1; x1 = rotl32(x1, (r)); x1 ^= x0; }
  TFR(13) TFR(15) TFR(26) TFR(6)
  x0 += ks1; x1 += ks2 + 1u;
  TFR(17) TFR(29) TFR(16) TFR(24)
  x0 += ks2; x1 += ks0 + 2u;
  TFR(13) TFR(15) TFR(26) TFR(6)
  x0 += ks0; x1 += ks1 + 3u;
  TFR(17) TFR(29) TFR(16) TFR(24)
  x0 += ks1; x1 += ks2 + 4u;
  TFR(13) TFR(15) TFR(26) TFR(6)
  x0 += ks2; x1 += ks0 + 5u;
#undef TFR
}

// jax.random.normal f32: u in [0,1) from top 23 bits; v = max(lo, u*2+lo),
// lo = nextafter(-1,0); z = sqrt(2)*erfinv(v) with XLA ErfInv32 (Giles) poly.
__device__ __forceinline__ float jax_normal_from_bits(uint32_t bits) {
  float u = __uint_as_float((bits >> 9) | 0x3f800000u) - 1.0f;
  const float lo = -0.99999994f;           // nextafter(-1, 0)
  float v = fmaxf(lo, fmaf(u, 2.0f, lo));
  float w = -log1pf(-v * v);
  float p;
  if (w < 5.0f) {
    w -= 2.5f;
    p = 2.81022636e-08f;
    p = fmaf(p, w, 3.43273939e-07f);
    p = fmaf(p, w, -3.5233877e-06f);
    p = fmaf(p, w, -4.39150654e-06f);
    p = fmaf(p, w, 0.00021858087f);
    p = fmaf(p, w, -0.00125372503f);
    p = fmaf(p, w, -0.00417768164f);
    p = fmaf(p, w, 0.246640727f);
    p = fmaf(p, w, 1.50140941f);
  } else {
    w = sqrtf(w) - 3.0f;
    p = -0.000200214257f;
    p = fmaf(p, w, 0.000100950558f);
    p = fmaf(p, w, 0.00134934322f);
    p = fmaf(p, w, -0.00367342844f);
    p = fmaf(p, w, 0.00573950773f);
    p = fmaf(p, w, -0.0076224613f);
    p = fmaf(p, w, 0.00943887047f);
    p = fmaf(p, w, 1.00167406f);
    p = fmaf(p, w, 2.83297682f);
  }
  return 1.41421356f * (p * v);
}

// Fused NAF forward. Block = 256 rows. X staged through LDS in 16 K-tiles of
// 32 cols with COALESCED loads (8 lanes per 128B row-chunk -> 8 transactions
// per wave-instr instead of 64 for the old per-lane 2KB-strided reads).
__global__ __launch_bounds__(TPB, 3) void naf_fused(
    const float* __restrict__ X, const float* __restrict__ RL,
    const float* __restrict__ act,
    const float* __restrict__ W1, const float* __restrict__ b1,
    const float* __restrict__ W2, const float* __restrict__ b2,
    const float* __restrict__ Wv, const float* __restrict__ bv,
    const float* __restrict__ Wmu, const float* __restrict__ bmu,
    const float* __restrict__ WL, const float* __restrict__ bL,
    float* __restrict__ out, int N) {
  __shared__ float sX[TPB * XPITCH];   // 36 KB: X tile [256 rows][32 cols + pad]
  __shared__ float sW1t[KT * HD];      // 4 KB: W1 K-tile [32][32]
  __shared__ float sW2[HD * HD];       // 4 KB
  __shared__ float sWmu[HD * AD];      // [k][a]
  __shared__ float sWLd[HD * AD];      // diag columns of WL, [k][a]
  __shared__ float sWv[HD];
  __shared__ float sb1[HD], sb2[HD], sbmu[AD], sbLd[AD];
  __shared__ float sbv;

  const int tid = threadIdx.x;

  // ---- stage small weights once (covered by first tile barrier) ----
  for (int i = tid; i < HD * HD; i += TPB) sW2[i] = W2[i];
  for (int i = tid; i < HD * AD; i += TPB) {
    sWmu[i] = Wmu[i];
    int k = i >> 3, a = i & 7;
    sWLd[i] = WL[k * 36 + ((a * a + 3 * a) >> 1)];  // tril diag index a(a+3)/2
  }
  if (tid < HD) { sWv[tid] = Wv[tid]; sb1[tid] = b1[tid]; sb2[tid] = b2[tid]; }
  if (tid < AD) { sbmu[tid] = bmu[tid]; sbLd[tid] = bL[(tid * tid + 3 * tid) >> 1]; }
  if (tid == 0) sbv = bv[0];

  const int R0 = blockIdx.x * TPB;
  const int row = R0 + tid;
  const bool active = row < N;

  const float4* Xv = reinterpret_cast<const float4*>(X);      // row stride 128
  const float4* W1v = reinterpret_cast<const float4*>(W1);    // [512][8] float4

  const int rl = tid >> 3;   // staging: local row 0..31 (+32 per iter)
  const int c4 = tid & 7;    // staging: float4 col 0..7 within tile

  float acc[HD];
#pragma unroll
  for (int c = 0; c < HD; ++c) acc[c] = 0.0f;

  // ---- layer 1: X[row,:] @ W1 over 16 LDS-staged K-tiles ----
  for (int kt = 0; kt < NTILE; ++kt) {
    __syncthreads();  // previous tile's readers done (also orders small staging)
    // stage W1 tile: rows kt*32..+31, contiguous 4KB
    *reinterpret_cast<float4*>(&sW1t[tid * 4]) = W1v[kt * (KT * HD / 4) + tid];
    // stage X tile: [256][32] floats, 8 iters, fully 128B-coalesced
#pragma unroll
    for (int it = 0; it < 8; ++it) {
      const int r = R0 + rl + it * 32;
      const int rs = r < N ? r : (N - 1);
      float4 v = Xv[(size_t)rs * (FDIM / 4) + kt * (KT / 4) + c4];
      *reinterpret_cast<float4*>(&sX[(rl + it * 32) * XPITCH + c4 * 4]) = v;
    }
    __syncthreads();
    if (active) {
      const float4* xrow = reinterpret_cast<const float4*>(&sX[tid * XPITCH]);
      const float4* w1t = reinterpret_cast<const float4*>(sW1t);
#pragma unroll
      for (int j = 0; j < KT / 4; ++j) {
        float4 xv = xrow[j];
        float xs[4] = {xv.x, xv.y, xv.z, xv.w};
#pragma unroll
        for (int jj = 0; jj < 4; ++jj) {
          const int base = (j * 4 + jj) * (HD / 4);
#pragma unroll
          for (int q = 0; q < HD / 4; ++q) {
            float4 wv = w1t[base + q];  // wave-uniform -> LDS broadcast
            acc[4 * q + 0] = fmaf(xs[jj], wv.x, acc[4 * q + 0]);
            acc[4 * q + 1] = fmaf(xs[jj], wv.y, acc[4 * q + 1]);
            acc[4 * q + 2] = fmaf(xs[jj], wv.z, acc[4 * q + 2]);
            acc[4 * q + 3] = fmaf(xs[jj], wv.w, acc[4 * q + 3]);
          }
        }
      }
    }
  }
  if (!active) return;  // no __syncthreads below this point

  float h1[HD];
#pragma unroll
  for (int c = 0; c < HD; ++c) h1[c] = fmaxf(acc[c] + sb1[c], 0.0f);

  // ---- layer 2: 32x32 ----
#pragma unroll
  for (int c = 0; c < HD; ++c) acc[c] = 0.0f;
  {
    const float4* w2v = reinterpret_cast<const float4*>(sW2);
#pragma unroll 4
    for (int k = 0; k < HD; ++k) {
      const float hk = h1[k];
#pragma unroll
      for (int q = 0; q < HD / 4; ++q) {
        float4 wv = w2v[k * (HD / 4) + q];
        acc[4 * q + 0] = fmaf(hk, wv.x, acc[4 * q + 0]);
        acc[4 * q + 1] = fmaf(hk, wv.y, acc[4 * q + 1]);
        acc[4 * q + 2] = fmaf(hk, wv.z, acc[4 * q + 2]);
        acc[4 * q + 3] = fmaf(hk, wv.w, acc[4 * q + 3]);
      }
    }
  }
  float h2[HD];
#pragma unroll
  for (int c = 0; c < HD; ++c) h2[c] = fmaxf(acc[c] + sb2[c], 0.0f);

  // ---- heads: value, mu (8), L-diagonal (8) ----
  float vacc = 0.0f;
  float mua[AD], dva[AD];
#pragma unroll
  for (int a = 0; a < AD; ++a) { mua[a] = 0.0f; dva[a] = 0.0f; }
#pragma unroll 4
  for (int k = 0; k < HD; ++k) {
    const float hk = h2[k];
    vacc = fmaf(hk, sWv[k], vacc);
#pragma unroll
    for (int a = 0; a < AD; ++a) {
      mua[a] = fmaf(hk, sWmu[k * AD + a], mua[a]);
      dva[a] = fmaf(hk, sWLd[k * AD + a], dva[a]);
    }
  }
  vacc += sbv;

  // ---- diagonal NAF closed form + Threefry sampling (partitionable) ----
  const float actn = act[row];
  const float rl_mask = RL[row];
  float adv = 0.0f;
  float smp[AD];
#pragma unroll
  for (int a = 0; a < AD; ++a) {
    const float mu = tanhf(mua[a] + sbmu[a]);
    const float dd = tanhf(dva[a] + sbLd[a]);
    const float ld = expf(dd);     // L diagonal; P_aa = ld^2; Lc_aa = 1/ld
    const float am = actn - mu;
    adv = fmaf(am * am, ld * ld, adv);
    // jax_threefry_partitionable: counter = (hi32(e), lo32(e)) = (0, e);
    // 32-bit bits = out0 ^ out1.
    const uint32_t e = (uint32_t)row * AD + (uint32_t)a;
    uint32_t x0 = 0u;
    uint32_t x1 = e;
    tf2x32_key42(x0, x1);
    const float z = jax_normal_from_bits(x0 ^ x1);
    float s = fmaf(z, 1.0f / ld, mu);
    s = fminf(fmaxf(s, -1.0f), 1.0f) * rl_mask;
    smp[a] = s;
  }
  const float q = fmaf(-0.5f, adv, vacc);

  float4* so = reinterpret_cast<float4*>(out) + (size_t)row * 2;
  so[0] = make_float4(smp[0], smp[1], smp[2], smp[3]);
  so[1] = make_float4(smp[4], smp[5], smp[6], smp[7]);
  out[(size_t)N * AD + row] = q;                  // Q
  out[(size_t)N * AD + (size_t)N + row] = vacc;   // value
}

extern "C" void kernel_launch(void* const* d_in, const int* in_sizes, int n_in,
                              void* d_out, int out_size, void* d_ws, size_t ws_size,
                              hipStream_t stream) {
  const float* X   = (const float*)d_in[0];
  const float* RL  = (const float*)d_in[1];
  const float* act = (const float*)d_in[2];
  const float* W1  = (const float*)d_in[3];
  const float* b1  = (const float*)d_in[4];
  const float* W2  = (const float*)d_in[5];
  const float* b2  = (const float*)d_in[6];
  const float* Wv  = (const float*)d_in[7];
  const float* bv  = (const float*)d_in[8];
  const float* Wmu = (const float*)d_in[9];
  const float* bmu = (const float*)d_in[10];
  const float* WL  = (const float*)d_in[11];
  const float* bL  = (const float*)d_in[12];
  const int N = in_sizes[1];  // RL_indice length
  const int blocks = (N + TPB - 1) / TPB;
  hipLaunchKernelGGL(naf_fused, dim3(blocks), dim3(TPB), 0, stream,
                     X, RL, act, W1, b1, W2, b2, Wv, bv, Wmu, bmu, WL, bL,
                     (float*)d_out, N);
}

// Round 4
// 167.626 us; speedup vs baseline: 1.3291x; 1.2169x over previous
//
#include <hip/hip_runtime.h>
#include <stdint.h>

#define TPB 256
#define FDIM 512
#define HD 32
#define AD 8
#define RPB 256      // rows per block (4 waves x 64 rows)
#define H1PITCH 36   // h1 LDS pitch (floats): 144B rows, 16B-aligned

typedef __bf16 bf16x8 __attribute__((ext_vector_type(8)));
typedef float f32x4 __attribute__((ext_vector_type(4)));
typedef uint32_t u32x4 __attribute__((ext_vector_type(4)));

__device__ __forceinline__ uint32_t rotl32(uint32_t x, int r) {
  return (x << r) | (x >> (32 - r));
}

// Threefry-2x32 with key (0, 42) == jax.random.key(42); 20 rounds.
__device__ __forceinline__ void tf2x32_key42(uint32_t& x0, uint32_t& x1) {
  const uint32_t ks0 = 0u, ks1 = 42u, ks2 = 0x1BD11BDAu ^ 0u ^ 42u;
  x0 += ks0; x1 += ks1;
#define TFR(r) { x0 += x1; x1 = rotl32(x1, (r)); x1 ^= x0; }
  TFR(13) TFR(15) TFR(26) TFR(6)
  x0 += ks1; x1 += ks2 + 1u;
  TFR(17) TFR(29) TFR(16) TFR(24)
  x0 += ks2; x1 += ks0 + 2u;
  TFR(13) TFR(15) TFR(26) TFR(6)
  x0 += ks0; x1 += ks1 + 3u;
  TFR(17) TFR(29) TFR(16) TFR(24)
  x0 += ks1; x1 += ks2 + 4u;
  TFR(13) TFR(15) TFR(26) TFR(6)
  x0 += ks2; x1 += ks0 + 5u;
#undef TFR
}

// jax.random.normal f32 from raw bits (XLA ErfInv32 / Giles polynomial).
__device__ __forceinline__ float jax_normal_from_bits(uint32_t bits) {
  float u = __uint_as_float((bits >> 9) | 0x3f800000u) - 1.0f;
  const float lo = -0.99999994f;           // nextafter(-1, 0)
  float v = fmaxf(lo, fmaf(u, 2.0f, lo));
  float w = -log1pf(-v * v);
  float p;
  if (w < 5.0f) {
    w -= 2.5f;
    p = 2.81022636e-08f;
    p = fmaf(p, w, 3.43273939e-07f);
    p = fmaf(p, w, -3.5233877e-06f);
    p = fmaf(p, w, -4.39150654e-06f);
    p = fmaf(p, w, 0.00021858087f);
    p = fmaf(p, w, -0.00125372503f);
    p = fmaf(p, w, -0.00417768164f);
    p = fmaf(p, w, 0.246640727f);
    p = fmaf(p, w, 1.50140941f);
  } else {
    w = sqrtf(w) - 3.0f;
    p = -0.000200214257f;
    p = fmaf(p, w, 0.000100950558f);
    p = fmaf(p, w, 0.00134934322f);
    p = fmaf(p, w, -0.00367342844f);
    p = fmaf(p, w, 0.00573950773f);
    p = fmaf(p, w, -0.0076224613f);
    p = fmaf(p, w, 0.00943887047f);
    p = fmaf(p, w, 1.00167406f);
    p = fmaf(p, w, 2.83297682f);
  }
  return 1.41421356f * (p * v);
}

// pack two f32 -> one u32 of two bf16 (RNE)
__device__ __forceinline__ uint32_t bf2(float a, float b) {
  uint32_t ua = __float_as_uint(a);
  uint32_t ub = __float_as_uint(b);
  ua = (ua + 0x7fffu + ((ua >> 16) & 1u)) >> 16;
  ub = (ub + 0x7fffu + ((ub >> 16) & 1u)) >> 16;
  return ua | (ub << 16);
}

__device__ __forceinline__ bf16x8 pack8(float4 a, float4 b) {
  u32x4 r;
  r.x = bf2(a.x, a.y);
  r.y = bf2(a.z, a.w);
  r.z = bf2(b.x, b.y);
  r.w = bf2(b.z, b.w);
  return __builtin_bit_cast(bf16x8, r);
}

// Layer 1 via bf16 MFMA (wave = 64 rows x 32 cols, K=512, W1 in VGPRs in two
// halves); h1 handoff through LDS; layer 2 / heads / NAF tail scalar per row.
__global__ __launch_bounds__(TPB, 3) void naf_fused(
    const float* __restrict__ X, const float* __restrict__ RL,
    const float* __restrict__ act,
    const float* __restrict__ W1, const float* __restrict__ b1,
    const float* __restrict__ W2, const float* __restrict__ b2,
    const float* __restrict__ Wv, const float* __restrict__ bv,
    const float* __restrict__ Wmu, const float* __restrict__ bmu,
    const float* __restrict__ WL, const float* __restrict__ bL,
    float* __restrict__ out, int N) {
  __shared__ float sh1[RPB * H1PITCH];  // 36 KB h1 handoff
  __shared__ float sW2[HD * HD];        // 4 KB
  __shared__ float sWmu[HD * AD];       // [k][a]
  __shared__ float sWLd[HD * AD];       // diag columns of WL, [k][a]
  __shared__ float sWv[HD];
  __shared__ float sb1[HD], sb2[HD], sbmu[AD], sbLd[AD];
  __shared__ float sbv;

  const int tid = threadIdx.x;

  // ---- stage small weights once ----
  for (int i = tid; i < HD * HD; i += TPB) sW2[i] = W2[i];
  for (int i = tid; i < HD * AD; i += TPB) {
    sWmu[i] = Wmu[i];
    int k = i >> 3, a = i & 7;
    sWLd[i] = WL[k * 36 + ((a * a + 3 * a) >> 1)];  // tril diag index a(a+3)/2
  }
  if (tid < HD) { sWv[tid] = Wv[tid]; sb1[tid] = b1[tid]; sb2[tid] = b2[tid]; }
  if (tid < AD) { sbmu[tid] = bmu[tid]; sbLd[tid] = bL[(tid * tid + 3 * tid) >> 1]; }
  if (tid == 0) sbv = bv[0];
  __syncthreads();

  const int lane = tid & 63;
  const int wid  = tid >> 6;
  const int llo  = lane & 15;   // A row / B col within 16-tile
  const int lhi  = lane >> 4;   // k-group (x8)
  const int R0   = blockIdx.x * RPB + wid * 64;

  // clamped row pointers for the wave's 4 m-tiles
  const float* xb[4];
#pragma unroll
  for (int mt = 0; mt < 4; ++mt) {
    int r = R0 + mt * 16 + llo;
    r = r < N ? r : (N - 1);
    xb[mt] = X + (size_t)r * FDIM + lhi * 8;
  }
  const float* w1p = W1 + (lhi * 8) * HD + llo;

  f32x4 acc[4][2];
#pragma unroll
  for (int mt = 0; mt < 4; ++mt)
#pragma unroll
    for (int nt = 0; nt < 2; ++nt)
      acc[mt][nt] = (f32x4){0.0f, 0.0f, 0.0f, 0.0f};

#pragma unroll 1
  for (int hf = 0; hf < 2; ++hf) {
    // B-fragments for this K-half: W1[k][col], k = kc*32 + lhi*8 + j
    bf16x8 bfrag[8][2];
#pragma unroll
    for (int kc8 = 0; kc8 < 8; ++kc8) {
#pragma unroll
      for (int nt = 0; nt < 2; ++nt) {
        const float* wp = w1p + (size_t)((hf * 8 + kc8) * 32) * HD + nt * 16;
        float4 v0, v1;
        v0.x = wp[0 * HD]; v0.y = wp[1 * HD]; v0.z = wp[2 * HD]; v0.w = wp[3 * HD];
        v1.x = wp[4 * HD]; v1.y = wp[5 * HD]; v1.z = wp[6 * HD]; v1.w = wp[7 * HD];
        bfrag[kc8][nt] = pack8(v0, v1);
      }
    }
#pragma unroll
    for (int kc8 = 0; kc8 < 8; ++kc8) {
      bf16x8 afrag[4];
#pragma unroll
      for (int mt = 0; mt < 4; ++mt) {
        const float* xp = xb[mt] + (hf * 8 + kc8) * 32;
        float4 x0 = *reinterpret_cast<const float4*>(xp);
        float4 x1 = *reinterpret_cast<const float4*>(xp + 4);
        afrag[mt] = pack8(x0, x1);
      }
#pragma unroll
      for (int mt = 0; mt < 4; ++mt)
#pragma unroll
        for (int nt = 0; nt < 2; ++nt)
          acc[mt][nt] = __builtin_amdgcn_mfma_f32_16x16x32_bf16(
              afrag[mt], bfrag[kc8][nt], acc[mt][nt], 0, 0, 0);
    }
  }

  // bias + ReLU; scatter C-layout tile to sh1 (2-way bank aliasing = free)
  {
    const float b1c0 = sb1[llo], b1c1 = sb1[16 + llo];
#pragma unroll
    for (int mt = 0; mt < 4; ++mt) {
#pragma unroll
      for (int nt = 0; nt < 2; ++nt) {
        const float bc = nt ? b1c1 : b1c0;
        const int cc = nt * 16 + llo;
#pragma unroll
        for (int i = 0; i < 4; ++i) {
          const int rl = wid * 64 + mt * 16 + lhi * 4 + i;
          sh1[rl * H1PITCH + cc] = fmaxf(acc[mt][nt][i] + bc, 0.0f);
        }
      }
    }
  }
  __syncthreads();

  // ---- finalize: thread t owns row R0block + t ----
  const int row = blockIdx.x * RPB + tid;
  if (row >= N) return;  // no __syncthreads below

  float h1v[HD];
  {
    const float4* xr = reinterpret_cast<const float4*>(&sh1[tid * H1PITCH]);
#pragma unroll
    for (int q = 0; q < HD / 4; ++q) {
      float4 t = xr[q];
      h1v[4 * q] = t.x; h1v[4 * q + 1] = t.y;
      h1v[4 * q + 2] = t.z; h1v[4 * q + 3] = t.w;
    }
  }

  // layer 2: 32x32
  float acc2[HD];
#pragma unroll
  for (int c = 0; c < HD; ++c) acc2[c] = 0.0f;
  {
    const float4* w2v = reinterpret_cast<const float4*>(sW2);
#pragma unroll 4
    for (int k = 0; k < HD; ++k) {
      const float hk = h1v[k];
#pragma unroll
      for (int q = 0; q < HD / 4; ++q) {
        float4 wv = w2v[k * (HD / 4) + q];
        acc2[4 * q + 0] = fmaf(hk, wv.x, acc2[4 * q + 0]);
        acc2[4 * q + 1] = fmaf(hk, wv.y, acc2[4 * q + 1]);
        acc2[4 * q + 2] = fmaf(hk, wv.z, acc2[4 * q + 2]);
        acc2[4 * q + 3] = fmaf(hk, wv.w, acc2[4 * q + 3]);
      }
    }
  }
  float h2[HD];
#pragma unroll
  for (int c = 0; c < HD; ++c) h2[c] = fmaxf(acc2[c] + sb2[c], 0.0f);

  // heads: value, mu (8), L-diagonal (8) — float4 LDS reads
  float vacc = 0.0f;
  float mua[AD], dva[AD];
#pragma unroll
  for (int a = 0; a < AD; ++a) { mua[a] = 0.0f; dva[a] = 0.0f; }
  {
    const float4* wmu4 = reinterpret_cast<const float4*>(sWmu);
    const float4* wld4 = reinterpret_cast<const float4*>(sWLd);
#pragma unroll 4
    for (int k = 0; k < HD; ++k) {
      const float hk = h2[k];
      vacc = fmaf(hk, sWv[k], vacc);
      float4 m0 = wmu4[2 * k], m1 = wmu4[2 * k + 1];
      float4 l0 = wld4[2 * k], l1 = wld4[2 * k + 1];
      mua[0] = fmaf(hk, m0.x, mua[0]); mua[1] = fmaf(hk, m0.y, mua[1]);
      mua[2] = fmaf(hk, m0.z, mua[2]); mua[3] = fmaf(hk, m0.w, mua[3]);
      mua[4] = fmaf(hk, m1.x, mua[4]); mua[5] = fmaf(hk, m1.y, mua[5]);
      mua[6] = fmaf(hk, m1.z, mua[6]); mua[7] = fmaf(hk, m1.w, mua[7]);
      dva[0] = fmaf(hk, l0.x, dva[0]); dva[1] = fmaf(hk, l0.y, dva[1]);
      dva[2] = fmaf(hk, l0.z, dva[2]); dva[3] = fmaf(hk, l0.w, dva[3]);
      dva[4] = fmaf(hk, l1.x, dva[4]); dva[5] = fmaf(hk, l1.y, dva[5]);
      dva[6] = fmaf(hk, l1.z, dva[6]); dva[7] = fmaf(hk, l1.w, dva[7]);
    }
  }
  vacc += sbv;

  // diagonal NAF closed form + Threefry sampling (partitionable)
  const float actn = act[row];
  const float rl_mask = RL[row];
  float adv = 0.0f;
  float smp[AD];
#pragma unroll
  for (int a = 0; a < AD; ++a) {
    const float mu = tanhf(mua[a] + sbmu[a]);
    const float dd = tanhf(dva[a] + sbLd[a]);
    const float ld = expf(dd);     // L diagonal; P_aa = ld^2; Lc_aa = 1/ld
    const float am = actn - mu;
    adv = fmaf(am * am, ld * ld, adv);
    const uint32_t e = (uint32_t)row * AD + (uint32_t)a;
    uint32_t x0 = 0u;
    uint32_t x1 = e;
    tf2x32_key42(x0, x1);
    const float z = jax_normal_from_bits(x0 ^ x1);
    float s = fmaf(z, 1.0f / ld, mu);
    s = fminf(fmaxf(s, -1.0f), 1.0f) * rl_mask;
    smp[a] = s;
  }
  const float q = fmaf(-0.5f, adv, vacc);

  float4* so = reinterpret_cast<float4*>(out) + (size_t)row * 2;
  so[0] = make_float4(smp[0], smp[1], smp[2], smp[3]);
  so[1] = make_float4(smp[4], smp[5], smp[6], smp[7]);
  out[(size_t)N * AD + row] = q;                  // Q
  out[(size_t)N * AD + (size_t)N + row] = vacc;   // value
}

extern "C" void kernel_launch(void* const* d_in, const int* in_sizes, int n_in,
                              void* d_out, int out_size, void* d_ws, size_t ws_size,
                              hipStream_t stream) {
  const float* X   = (const float*)d_in[0];
  const float* RL  = (const float*)d_in[1];
  const float* act = (const float*)d_in[2];
  const float* W1  = (const float*)d_in[3];
  const float* b1  = (const float*)d_in[4];
  const float* W2  = (const float*)d_in[5];
  const float* b2  = (const float*)d_in[6];
  const float* Wv  = (const float*)d_in[7];
  const float* bv  = (const float*)d_in[8];
  const float* Wmu = (const float*)d_in[9];
  const float* bmu = (const float*)d_in[10];
  const float* WL  = (const float*)d_in[11];
  const float* bL  = (const float*)d_in[12];
  const int N = in_sizes[1];  // RL_indice length
  const int blocks = (N + RPB - 1) / RPB;
  hipLaunchKernelGGL(naf_fused, dim3(blocks), dim3(TPB), 0, stream,
                     X, RL, act, W1, b1, W2, b2, Wv, bv, Wmu, bmu, WL, bL,
                     (float*)d_out, N);
}

// Round 5
// 155.143 us; speedup vs baseline: 1.4361x; 1.0805x over previous
//
#include <hip/hip_runtime.h>
#include <stdint.h>

#define TPB 256
#define FDIM 512
#define HD 32
#define AD 8
#define RPB 256            // rows per block (4 waves x 64 rows)
#define KTILE 64           // f32 K-cols staged per tile
#define NKT (FDIM / KTILE) // 8 tiles
#define H1PITCH 36         // h1 LDS pitch (floats)

typedef __bf16 bf16x8 __attribute__((ext_vector_type(8)));
typedef float f32x4 __attribute__((ext_vector_type(4)));
typedef uint32_t u32x4 __attribute__((ext_vector_type(4)));

__device__ __forceinline__ uint32_t rotl32(uint32_t x, int r) {
  return (x << r) | (x >> (32 - r));
}

// Threefry-2x32 with key (0, 42) == jax.random.key(42); 20 rounds.
__device__ __forceinline__ void tf2x32_key42(uint32_t& x0, uint32_t& x1) {
  const uint32_t ks0 = 0u, ks1 = 42u, ks2 = 0x1BD11BDAu ^ 0u ^ 42u;
  x0 += ks0; x1 += ks1;
#define TFR(r) { x0 += x1; x1 = rotl32(x1, (r)); x1 ^= x0; }
  TFR(13) TFR(15) TFR(26) TFR(6)
  x0 += ks1; x1 += ks2 + 1u;
  TFR(17) TFR(29) TFR(16) TFR(24)
  x0 += ks2; x1 += ks0 + 2u;
  TFR(13) TFR(15) TFR(26) TFR(6)
  x0 += ks0; x1 += ks1 + 3u;
  TFR(17) TFR(29) TFR(16) TFR(24)
  x0 += ks1; x1 += ks2 + 4u;
  TFR(13) TFR(15) TFR(26) TFR(6)
  x0 += ks2; x1 += ks0 + 5u;
#undef TFR
}

// jax.random.normal f32 from raw bits (XLA ErfInv32 / Giles polynomial).
__device__ __forceinline__ float jax_normal_from_bits(uint32_t bits) {
  float u = __uint_as_float((bits >> 9) | 0x3f800000u) - 1.0f;
  const float lo = -0.99999994f;           // nextafter(-1, 0)
  float v = fmaxf(lo, fmaf(u, 2.0f, lo));
  float w = -log1pf(-v * v);
  float p;
  if (w < 5.0f) {
    w -= 2.5f;
    p = 2.81022636e-08f;
    p = fmaf(p, w, 3.43273939e-07f);
    p = fmaf(p, w, -3.5233877e-06f);
    p = fmaf(p, w, -4.39150654e-06f);
    p = fmaf(p, w, 0.00021858087f);
    p = fmaf(p, w, -0.00125372503f);
    p = fmaf(p, w, -0.00417768164f);
    p = fmaf(p, w, 0.246640727f);
    p = fmaf(p, w, 1.50140941f);
  } else {
    w = sqrtf(w) - 3.0f;
    p = -0.000200214257f;
    p = fmaf(p, w, 0.000100950558f);
    p = fmaf(p, w, 0.00134934322f);
    p = fmaf(p, w, -0.00367342844f);
    p = fmaf(p, w, 0.00573950773f);
    p = fmaf(p, w, -0.0076224613f);
    p = fmaf(p, w, 0.00943887047f);
    p = fmaf(p, w, 1.00167406f);
    p = fmaf(p, w, 2.83297682f);
  }
  return 1.41421356f * (p * v);
}

// pack two f32 -> one u32 of two bf16 (RNE)
__device__ __forceinline__ uint32_t bf2(float a, float b) {
  uint32_t ua = __float_as_uint(a);
  uint32_t ub = __float_as_uint(b);
  ua = (ua + 0x7fffu + ((ua >> 16) & 1u)) >> 16;
  ub = (ub + 0x7fffu + ((ub >> 16) & 1u)) >> 16;
  return ua | (ub << 16);
}

__device__ __forceinline__ bf16x8 pack8(float4 a, float4 b) {
  u32x4 r;
  r.x = bf2(a.x, a.y);
  r.y = bf2(a.z, a.w);
  r.z = bf2(b.x, b.y);
  r.w = bf2(b.z, b.w);
  return __builtin_bit_cast(bf16x8, r);
}

// Layer 1 via bf16 MFMA with X staged through LDS: coalesced dwordx4 global
// reads (dense 128B lines), f32->bf16 pack, XOR-swizzled ds_write_b64; A-frags
// are single ds_read_b128. W1 B-frags per tile from global (L2-hot), issued
// in the staging phase. h1 handoff aliases the X tile. Tail scalar per row.
__global__ __launch_bounds__(TPB, 3) void naf_fused(
    const float* __restrict__ X, const float* __restrict__ RL,
    const float* __restrict__ act,
    const float* __restrict__ W1, const float* __restrict__ b1,
    const float* __restrict__ W2, const float* __restrict__ b2,
    const float* __restrict__ Wv, const float* __restrict__ bv,
    const float* __restrict__ Wmu, const float* __restrict__ bmu,
    const float* __restrict__ WL, const float* __restrict__ bL,
    float* __restrict__ out, int N) {
  // union region: bf16 X tile [256 rows][128 B] (32 KB) / h1 [256][36] f32 (36 KB)
  __shared__ __align__(16) char sBig[RPB * H1PITCH * 4];
  __shared__ float sW2[HD * HD];        // 4 KB
  __shared__ float sWmu[HD * AD];       // [k][a]
  __shared__ float sWLd[HD * AD];       // diag columns of WL, [k][a]
  __shared__ float sWv[HD];
  __shared__ float sb1[HD], sb2[HD], sbmu[AD], sbLd[AD];
  __shared__ float sbv;

  const int tid = threadIdx.x;

  // ---- stage small weights once ----
  for (int i = tid; i < HD * HD; i += TPB) sW2[i] = W2[i];
  for (int i = tid; i < HD * AD; i += TPB) {
    sWmu[i] = Wmu[i];
    int k = i >> 3, a = i & 7;
    sWLd[i] = WL[k * 36 + ((a * a + 3 * a) >> 1)];  // tril diag index a(a+3)/2
  }
  if (tid < HD) { sWv[tid] = Wv[tid]; sb1[tid] = b1[tid]; sb2[tid] = b2[tid]; }
  if (tid < AD) { sbmu[tid] = bmu[tid]; sbLd[tid] = bL[(tid * tid + 3 * tid) >> 1]; }
  if (tid == 0) sbv = bv[0];

  const int lane = tid & 63;
  const int wid  = tid >> 6;
  const int llo  = lane & 15;   // A row / B col within 16-tile
  const int lhi  = lane >> 4;   // k-group (x8)
  const int R0   = blockIdx.x * RPB;

  const float4* Xv = reinterpret_cast<const float4*>(X);  // row stride 128 f4

  // staging coords: thread t covers (row = it*16 + rsub, float4-col c4)
  const int rsub = tid >> 4;    // 0..15
  const int c4   = tid & 15;    // 0..15 (16 float4 = 64 f32 per tile row)

  f32x4 acc[4][2];
#pragma unroll
  for (int mt = 0; mt < 4; ++mt)
#pragma unroll
    for (int nt = 0; nt < 2; ++nt)
      acc[mt][nt] = (f32x4){0.0f, 0.0f, 0.0f, 0.0f};

#pragma unroll 1
  for (int kt = 0; kt < NKT; ++kt) {
    __syncthreads();  // previous tile's readers done
    // ---- stage X tile: [256 rows][64 f32] -> bf16 LDS, swizzled ----
#pragma unroll
    for (int it = 0; it < 16; ++it) {
      const int rloc = it * 16 + rsub;
      int r = R0 + rloc;
      r = r < N ? r : (N - 1);
      float4 v = Xv[(size_t)r * (FDIM / 4) + kt * (KTILE / 4) + c4];
      uint2 pkd = make_uint2(bf2(v.x, v.y), bf2(v.z, v.w));
      const int boff = (c4 * 8) ^ ((rloc & 7) << 4);
      *reinterpret_cast<uint2*>(sBig + rloc * 128 + boff) = pkd;
    }
    // ---- W1 B-frags for this tile (global, L2-hot; latency hides in barrier) ----
    bf16x8 bfrag[2][2];
    {
      const float* w1p = W1 + (size_t)(kt * KTILE + lhi * 8) * HD + llo;
#pragma unroll
      for (int kc = 0; kc < 2; ++kc) {
#pragma unroll
        for (int nt = 0; nt < 2; ++nt) {
          const float* wp = w1p + (size_t)(kc * 32) * HD + nt * 16;
          float4 v0, v1;
          v0.x = wp[0 * HD]; v0.y = wp[1 * HD]; v0.z = wp[2 * HD]; v0.w = wp[3 * HD];
          v1.x = wp[4 * HD]; v1.y = wp[5 * HD]; v1.z = wp[6 * HD]; v1.w = wp[7 * HD];
          bfrag[kc][nt] = pack8(v0, v1);
        }
      }
    }
    __syncthreads();
    // ---- A-frags from LDS + MFMA ----
#pragma unroll
    for (int kc = 0; kc < 2; ++kc) {
#pragma unroll
      for (int mt = 0; mt < 4; ++mt) {
        const int rloc = wid * 64 + mt * 16 + llo;
        const int boff = (kc * 64 + lhi * 16) ^ ((rloc & 7) << 4);
        bf16x8 afrag =
            *reinterpret_cast<const bf16x8*>(sBig + rloc * 128 + boff);
#pragma unroll
        for (int nt = 0; nt < 2; ++nt)
          acc[mt][nt] = __builtin_amdgcn_mfma_f32_16x16x32_bf16(
              afrag, bfrag[kc][nt], acc[mt][nt], 0, 0, 0);
      }
    }
  }

  __syncthreads();  // all A-frag reads done; safe to overwrite sBig with h1
  float* sh1 = reinterpret_cast<float*>(sBig);

  // bias + ReLU; scatter C-layout tile (col=lane&15, row=lhi*4+i) to sh1
  {
    const float b1c0 = sb1[llo], b1c1 = sb1[16 + llo];
#pragma unroll
    for (int mt = 0; mt < 4; ++mt) {
#pragma unroll
      for (int nt = 0; nt < 2; ++nt) {
        const float bc = nt ? b1c1 : b1c0;
        const int cc = nt * 16 + llo;
#pragma unroll
        for (int i = 0; i < 4; ++i) {
          const int rl = wid * 64 + mt * 16 + lhi * 4 + i;
          sh1[rl * H1PITCH + cc] = fmaxf(acc[mt][nt][i] + bc, 0.0f);
        }
      }
    }
  }
  __syncthreads();

  // ---- finalize: thread t owns row R0 + t ----
  const int row = R0 + tid;
  if (row >= N) return;  // no __syncthreads below

  float h1v[HD];
  {
    const float4* xr = reinterpret_cast<const float4*>(&sh1[tid * H1PITCH]);
#pragma unroll
    for (int q = 0; q < HD / 4; ++q) {
      float4 t = xr[q];
      h1v[4 * q] = t.x; h1v[4 * q + 1] = t.y;
      h1v[4 * q + 2] = t.z; h1v[4 * q + 3] = t.w;
    }
  }

  // layer 2: 32x32
  float acc2[HD];
#pragma unroll
  for (int c = 0; c < HD; ++c) acc2[c] = 0.0f;
  {
    const float4* w2v = reinterpret_cast<const float4*>(sW2);
#pragma unroll 4
    for (int k = 0; k < HD; ++k) {
      const float hk = h1v[k];
#pragma unroll
      for (int q = 0; q < HD / 4; ++q) {
        float4 wv = w2v[k * (HD / 4) + q];
        acc2[4 * q + 0] = fmaf(hk, wv.x, acc2[4 * q + 0]);
        acc2[4 * q + 1] = fmaf(hk, wv.y, acc2[4 * q + 1]);
        acc2[4 * q + 2] = fmaf(hk, wv.z, acc2[4 * q + 2]);
        acc2[4 * q + 3] = fmaf(hk, wv.w, acc2[4 * q + 3]);
      }
    }
  }
  float h2[HD];
#pragma unroll
  for (int c = 0; c < HD; ++c) h2[c] = fmaxf(acc2[c] + sb2[c], 0.0f);

  // heads: value, mu (8), L-diagonal (8)
  float vacc = 0.0f;
  float mua[AD], dva[AD];
#pragma unroll
  for (int a = 0; a < AD; ++a) { mua[a] = 0.0f; dva[a] = 0.0f; }
  {
    const float4* wmu4 = reinterpret_cast<const float4*>(sWmu);
    const float4* wld4 = reinterpret_cast<const float4*>(sWLd);
#pragma unroll 4
    for (int k = 0; k < HD; ++k) {
      const float hk = h2[k];
      vacc = fmaf(hk, sWv[k], vacc);
      float4 m0 = wmu4[2 * k], m1 = wmu4[2 * k + 1];
      float4 l0 = wld4[2 * k], l1 = wld4[2 * k + 1];
      mua[0] = fmaf(hk, m0.x, mua[0]); mua[1] = fmaf(hk, m0.y, mua[1]);
      mua[2] = fmaf(hk, m0.z, mua[2]); mua[3] = fmaf(hk, m0.w, mua[3]);
      mua[4] = fmaf(hk, m1.x, mua[4]); mua[5] = fmaf(hk, m1.y, mua[5]);
      mua[6] = fmaf(hk, m1.z, mua[6]); mua[7] = fmaf(hk, m1.w, mua[7]);
      dva[0] = fmaf(hk, l0.x, dva[0]); dva[1] = fmaf(hk, l0.y, dva[1]);
      dva[2] = fmaf(hk, l0.z, dva[2]); dva[3] = fmaf(hk, l0.w, dva[3]);
      dva[4] = fmaf(hk, l1.x, dva[4]); dva[5] = fmaf(hk, l1.y, dva[5]);
      dva[6] = fmaf(hk, l1.z, dva[6]); dva[7] = fmaf(hk, l1.w, dva[7]);
    }
  }
  vacc += sbv;

  // diagonal NAF closed form + Threefry sampling (partitionable)
  const float actn = act[row];
  const float rl_mask = RL[row];
  float adv = 0.0f;
  float smp[AD];
#pragma unroll
  for (int a = 0; a < AD; ++a) {
    const float mu = tanhf(mua[a] + sbmu[a]);
    const float dd = tanhf(dva[a] + sbLd[a]);
    const float ld = expf(dd);     // L diagonal; P_aa = ld^2; Lc_aa = 1/ld
    const float am = actn - mu;
    adv = fmaf(am * am, ld * ld, adv);
    const uint32_t e = (uint32_t)row * AD + (uint32_t)a;
    uint32_t x0 = 0u;
    uint32_t x1 = e;
    tf2x32_key42(x0, x1);
    const float z = jax_normal_from_bits(x0 ^ x1);
    float s = fmaf(z, 1.0f / ld, mu);
    s = fminf(fmaxf(s, -1.0f), 1.0f) * rl_mask;
    smp[a] = s;
  }
  const float q = fmaf(-0.5f, adv, vacc);

  float4* so = reinterpret_cast<float4*>(out) + (size_t)row * 2;
  so[0] = make_float4(smp[0], smp[1], smp[2], smp[3]);
  so[1] = make_float4(smp[4], smp[5], smp[6], smp[7]);
  out[(size_t)N * AD + row] = q;                  // Q
  out[(size_t)N * AD + (size_t)N + row] = vacc;   // value
}

extern "C" void kernel_launch(void* const* d_in, const int* in_sizes, int n_in,
                              void* d_out, int out_size, void* d_ws, size_t ws_size,
                              hipStream_t stream) {
  const float* X   = (const float*)d_in[0];
  const float* RL  = (const float*)d_in[1];
  const float* act = (const float*)d_in[2];
  const float* W1  = (const float*)d_in[3];
  const float* b1  = (const float*)d_in[4];
  const float* W2  = (const float*)d_in[5];
  const float* b2  = (const float*)d_in[6];
  const float* Wv  = (const float*)d_in[7];
  const float* bv  = (const float*)d_in[8];
  const float* Wmu = (const float*)d_in[9];
  const float* bmu = (const float*)d_in[10];
  const float* WL  = (const float*)d_in[11];
  const float* bL  = (const float*)d_in[12];
  const int N = in_sizes[1];  // RL_indice length
  const int blocks = (N + RPB - 1) / RPB;
  hipLaunchKernelGGL(naf_fused, dim3(blocks), dim3(TPB), 0, stream,
                     X, RL, act, W1, b1, W2, b2, Wv, bv, Wmu, bmu, WL, bL,
                     (float*)d_out, N);
}

// Round 6
// 112.268 us; speedup vs baseline: 1.9845x; 1.3819x over previous
//
#include <hip/hip_runtime.h>
#include <stdint.h>

#define TPB 256
#define FDIM 512
#define HD 32
#define AD 8
#define RPB 256            // rows per block (4 waves x 64 rows)
#define KTILE 64           // f32 K-cols staged per tile
#define NKT (FDIM / KTILE) // 8 tiles
#define H1PITCH 36         // h1 LDS pitch (floats)

typedef __bf16 bf16x8 __attribute__((ext_vector_type(8)));
typedef float f32x4 __attribute__((ext_vector_type(4)));
typedef uint32_t u32x4 __attribute__((ext_vector_type(4)));

__device__ __forceinline__ uint32_t rotl32(uint32_t x, int r) {
  return (x << r) | (x >> (32 - r));
}

// Threefry-2x32 with key (0, 42) == jax.random.key(42); 20 rounds.
__device__ __forceinline__ void tf2x32_key42(uint32_t& x0, uint32_t& x1) {
  const uint32_t ks0 = 0u, ks1 = 42u, ks2 = 0x1BD11BDAu ^ 0u ^ 42u;
  x0 += ks0; x1 += ks1;
#define TFR(r) { x0 += x1; x1 = rotl32(x1, (r)); x1 ^= x0; }
  TFR(13) TFR(15) TFR(26) TFR(6)
  x0 += ks1; x1 += ks2 + 1u;
  TFR(17) TFR(29) TFR(16) TFR(24)
  x0 += ks2; x1 += ks0 + 2u;
  TFR(13) TFR(15) TFR(26) TFR(6)
  x0 += ks0; x1 += ks1 + 3u;
  TFR(17) TFR(29) TFR(16) TFR(24)
  x0 += ks1; x1 += ks2 + 4u;
  TFR(13) TFR(15) TFR(26) TFR(6)
  x0 += ks2; x1 += ks0 + 5u;
#undef TFR
}

// jax.random.normal f32 from raw bits (XLA ErfInv32 / Giles polynomial).
__device__ __forceinline__ float jax_normal_from_bits(uint32_t bits) {
  float u = __uint_as_float((bits >> 9) | 0x3f800000u) - 1.0f;
  const float lo = -0.99999994f;           // nextafter(-1, 0)
  float v = fmaxf(lo, fmaf(u, 2.0f, lo));
  float w = -log1pf(-v * v);
  float p;
  if (w < 5.0f) {
    w -= 2.5f;
    p = 2.81022636e-08f;
    p = fmaf(p, w, 3.43273939e-07f);
    p = fmaf(p, w, -3.5233877e-06f);
    p = fmaf(p, w, -4.39150654e-06f);
    p = fmaf(p, w, 0.00021858087f);
    p = fmaf(p, w, -0.00125372503f);
    p = fmaf(p, w, -0.00417768164f);
    p = fmaf(p, w, 0.246640727f);
    p = fmaf(p, w, 1.50140941f);
  } else {
    w = sqrtf(w) - 3.0f;
    p = -0.000200214257f;
    p = fmaf(p, w, 0.000100950558f);
    p = fmaf(p, w, 0.00134934322f);
    p = fmaf(p, w, -0.00367342844f);
    p = fmaf(p, w, 0.00573950773f);
    p = fmaf(p, w, -0.0076224613f);
    p = fmaf(p, w, 0.00943887047f);
    p = fmaf(p, w, 1.00167406f);
    p = fmaf(p, w, 2.83297682f);
  }
  return 1.41421356f * (p * v);
}

// pack two f32 -> one u32 of two bf16 (RNE)
__device__ __forceinline__ uint32_t bf2(float a, float b) {
  uint32_t ua = __float_as_uint(a);
  uint32_t ub = __float_as_uint(b);
  ua = (ua + 0x7fffu + ((ua >> 16) & 1u)) >> 16;
  ub = (ub + 0x7fffu + ((ub >> 16) & 1u)) >> 16;
  return ua | (ub << 16);
}

__device__ __forceinline__ bf16x8 pack8(float4 a, float4 b) {
  u32x4 r;
  r.x = bf2(a.x, a.y);
  r.y = bf2(a.z, a.w);
  r.z = bf2(b.x, b.y);
  r.w = bf2(b.z, b.w);
  return __builtin_bit_cast(bf16x8, r);
}

// Layer 1 via bf16 MFMA. Software-pipelined staging (T14): per K-tile,
// {ds_write regs -> LDS; issue next tile's global loads into regs; barrier;
// frag reads + MFMA; barrier} -- loads stay in flight across the whole
// iteration. W1 staged ONCE per block into LDS in fragment order (one
// conflict-free ds_read_b128 per B-frag). Tail scalar per row (unchanged).
__global__ __launch_bounds__(TPB, 2) void naf_fused(
    const float* __restrict__ X, const float* __restrict__ RL,
    const float* __restrict__ act,
    const float* __restrict__ W1, const float* __restrict__ b1,
    const float* __restrict__ W2, const float* __restrict__ b2,
    const float* __restrict__ Wv, const float* __restrict__ bv,
    const float* __restrict__ Wmu, const float* __restrict__ bmu,
    const float* __restrict__ WL, const float* __restrict__ bL,
    float* __restrict__ out, int N) {
  // union: bf16 X tile [256 rows][128 B] (32 KB) / h1 [256][36] f32 (36 KB)
  __shared__ __align__(16) char sBig[RPB * H1PITCH * 4];
  __shared__ __align__(16) char sW1f[32768];  // W1 bf16, fragment-ordered
  __shared__ float sW2[HD * HD];        // 4 KB
  __shared__ float sWmu[HD * AD];       // [k][a]
  __shared__ float sWLd[HD * AD];       // diag columns of WL, [k][a]
  __shared__ float sWv[HD];
  __shared__ float sb1[HD], sb2[HD], sbmu[AD], sbLd[AD];
  __shared__ float sbv;

  const int tid = threadIdx.x;
  const int lane = tid & 63;
  const int wid  = tid >> 6;
  const int llo  = lane & 15;   // A row / B col within 16-tile
  const int lhi  = lane >> 4;   // k-group (x8)
  const int R0   = blockIdx.x * RPB;

  const float4* Xv = reinterpret_cast<const float4*>(X);  // row stride 128 f4
  const int rsub = tid >> 4;    // staging row 0..15 (+16 per it)
  const int c4   = tid & 15;    // staging float4 col 0..15

  // ---- issue X tile 0 loads FIRST (fly during weight staging) ----
  float4 xreg[16];
#pragma unroll
  for (int it = 0; it < 16; ++it) {
    const int rloc = it * 16 + rsub;
    int r = R0 + rloc;
    r = r < N ? r : (N - 1);
    xreg[it] = Xv[(size_t)r * (FDIM / 4) + c4];
  }

  // ---- stage small weights ----
  for (int i = tid; i < HD * HD; i += TPB) sW2[i] = W2[i];
  for (int i = tid; i < HD * AD; i += TPB) {
    sWmu[i] = Wmu[i];
    int k = i >> 3, a = i & 7;
    sWLd[i] = WL[k * 36 + ((a * a + 3 * a) >> 1)];  // tril diag index a(a+3)/2
  }
  if (tid < HD) { sWv[tid] = Wv[tid]; sb1[tid] = b1[tid]; sb2[tid] = b2[tid]; }
  if (tid < AD) { sbmu[tid] = bmu[tid]; sbLd[tid] = bL[(tid * tid + 3 * tid) >> 1]; }
  if (tid == 0) sbv = bv[0];

  // ---- stage W1 in fragment order: group g = (ktile2*2+kc)*2... i.e.
  // g = f*2+nt where f = K-chunk-of-32 (0..15), nt = col-half (0..1).
  // chunk c (16B) = g*64 + lane_in_frag; frag lane holds W1[k0+j][col], j=0..7.
#pragma unroll
  for (int i = 0; i < 8; ++i) {
    const int c = i * TPB + tid;       // 0..2047
    const int g = c >> 6;
    const int ln = c & 63;
    const int k0 = (g >> 1) * 32 + (ln >> 4) * 8;
    const int col = (g & 1) * 16 + (ln & 15);
    const float* wp = W1 + (size_t)k0 * HD + col;
    float4 v0, v1;
    v0.x = wp[0 * HD]; v0.y = wp[1 * HD]; v0.z = wp[2 * HD]; v0.w = wp[3 * HD];
    v1.x = wp[4 * HD]; v1.y = wp[5 * HD]; v1.z = wp[6 * HD]; v1.w = wp[7 * HD];
    *reinterpret_cast<bf16x8*>(sW1f + (size_t)c * 16) = pack8(v0, v1);
  }

  f32x4 acc[4][2];
#pragma unroll
  for (int mt = 0; mt < 4; ++mt)
#pragma unroll
    for (int nt = 0; nt < 2; ++nt)
      acc[mt][nt] = (f32x4){0.0f, 0.0f, 0.0f, 0.0f};

#pragma unroll 1
  for (int kt = 0; kt < NKT; ++kt) {
    // ---- write current tile (regs -> bf16 LDS, XOR-swizzled) ----
    // WAR safe: previous iteration's barrier2 drained all tile readers.
#pragma unroll
    for (int it = 0; it < 16; ++it) {
      const int rloc = it * 16 + rsub;
      uint2 pkd = make_uint2(bf2(xreg[it].x, xreg[it].y),
                             bf2(xreg[it].z, xreg[it].w));
      const int boff = (c4 * 8) ^ ((rloc & 7) << 4);
      *reinterpret_cast<uint2*>(sBig + rloc * 128 + boff) = pkd;
    }
    // ---- issue next tile's loads; they fly across both barriers + MFMA ----
    if (kt + 1 < NKT) {
#pragma unroll
      for (int it = 0; it < 16; ++it) {
        const int rloc = it * 16 + rsub;
        int r = R0 + rloc;
        r = r < N ? r : (N - 1);
        xreg[it] = Xv[(size_t)r * (FDIM / 4) + (kt + 1) * 16 + c4];
      }
    }
    __syncthreads();
    // ---- B-frags: one conflict-free ds_read_b128 each ----
    bf16x8 bfrag[2][2];
#pragma unroll
    for (int kc = 0; kc < 2; ++kc)
#pragma unroll
      for (int nt = 0; nt < 2; ++nt) {
        const int g = (kt * 2 + kc) * 2 + nt;
        bfrag[kc][nt] =
            *reinterpret_cast<const bf16x8*>(sW1f + g * 1024 + lane * 16);
      }
    // ---- A-frags from swizzled LDS + MFMA ----
#pragma unroll
    for (int kc = 0; kc < 2; ++kc) {
#pragma unroll
      for (int mt = 0; mt < 4; ++mt) {
        const int rloc = wid * 64 + mt * 16 + llo;
        const int boff = (kc * 64 + lhi * 16) ^ ((rloc & 7) << 4);
        bf16x8 afrag =
            *reinterpret_cast<const bf16x8*>(sBig + rloc * 128 + boff);
#pragma unroll
        for (int nt = 0; nt < 2; ++nt)
          acc[mt][nt] = __builtin_amdgcn_mfma_f32_16x16x32_bf16(
              afrag, bfrag[kc][nt], acc[mt][nt], 0, 0, 0);
      }
    }
    __syncthreads();
  }

  float* sh1 = reinterpret_cast<float*>(sBig);  // safe: barrier2 drained readers

  // bias + ReLU; scatter C-layout tile (col=lane&15, row=lhi*4+i) to sh1
  {
    const float b1c0 = sb1[llo], b1c1 = sb1[16 + llo];
#pragma unroll
    for (int mt = 0; mt < 4; ++mt) {
#pragma unroll
      for (int nt = 0; nt < 2; ++nt) {
        const float bc = nt ? b1c1 : b1c0;
        const int cc = nt * 16 + llo;
#pragma unroll
        for (int i = 0; i < 4; ++i) {
          const int rl = wid * 64 + mt * 16 + lhi * 4 + i;
          sh1[rl * H1PITCH + cc] = fmaxf(acc[mt][nt][i] + bc, 0.0f);
        }
      }
    }
  }
  __syncthreads();

  // ---- finalize: thread t owns row R0 + t ----
  const int row = R0 + tid;
  if (row >= N) return;  // no __syncthreads below

  float h1v[HD];
  {
    const float4* xr = reinterpret_cast<const float4*>(&sh1[tid * H1PITCH]);
#pragma unroll
    for (int q = 0; q < HD / 4; ++q) {
      float4 t = xr[q];
      h1v[4 * q] = t.x; h1v[4 * q + 1] = t.y;
      h1v[4 * q + 2] = t.z; h1v[4 * q + 3] = t.w;
    }
  }

  // layer 2: 32x32
  float acc2[HD];
#pragma unroll
  for (int c = 0; c < HD; ++c) acc2[c] = 0.0f;
  {
    const float4* w2v = reinterpret_cast<const float4*>(sW2);
#pragma unroll 4
    for (int k = 0; k < HD; ++k) {
      const float hk = h1v[k];
#pragma unroll
      for (int q = 0; q < HD / 4; ++q) {
        float4 wv = w2v[k * (HD / 4) + q];
        acc2[4 * q + 0] = fmaf(hk, wv.x, acc2[4 * q + 0]);
        acc2[4 * q + 1] = fmaf(hk, wv.y, acc2[4 * q + 1]);
        acc2[4 * q + 2] = fmaf(hk, wv.z, acc2[4 * q + 2]);
        acc2[4 * q + 3] = fmaf(hk, wv.w, acc2[4 * q + 3]);
      }
    }
  }
  float h2[HD];
#pragma unroll
  for (int c = 0; c < HD; ++c) h2[c] = fmaxf(acc2[c] + sb2[c], 0.0f);

  // heads: value, mu (8), L-diagonal (8)
  float vacc = 0.0f;
  float mua[AD], dva[AD];
#pragma unroll
  for (int a = 0; a < AD; ++a) { mua[a] = 0.0f; dva[a] = 0.0f; }
  {
    const float4* wmu4 = reinterpret_cast<const float4*>(sWmu);
    const float4* wld4 = reinterpret_cast<const float4*>(sWLd);
#pragma unroll 4
    for (int k = 0; k < HD; ++k) {
      const float hk = h2[k];
      vacc = fmaf(hk, sWv[k], vacc);
      float4 m0 = wmu4[2 * k], m1 = wmu4[2 * k + 1];
      float4 l0 = wld4[2 * k], l1 = wld4[2 * k + 1];
      mua[0] = fmaf(hk, m0.x, mua[0]); mua[1] = fmaf(hk, m0.y, mua[1]);
      mua[2] = fmaf(hk, m0.z, mua[2]); mua[3] = fmaf(hk, m0.w, mua[3]);
      mua[4] = fmaf(hk, m1.x, mua[4]); mua[5] = fmaf(hk, m1.y, mua[5]);
      mua[6] = fmaf(hk, m1.z, mua[6]); mua[7] = fmaf(hk, m1.w, mua[7]);
      dva[0] = fmaf(hk, l0.x, dva[0]); dva[1] = fmaf(hk, l0.y, dva[1]);
      dva[2] = fmaf(hk, l0.z, dva[2]); dva[3] = fmaf(hk, l0.w, dva[3]);
      dva[4] = fmaf(hk, l1.x, dva[4]); dva[5] = fmaf(hk, l1.y, dva[5]);
      dva[6] = fmaf(hk, l1.z, dva[6]); dva[7] = fmaf(hk, l1.w, dva[7]);
    }
  }
  vacc += sbv;

  // diagonal NAF closed form + Threefry sampling (partitionable)
  const float actn = act[row];
  const float rl_mask = RL[row];
  float adv = 0.0f;
  float smp[AD];
#pragma unroll
  for (int a = 0; a < AD; ++a) {
    const float mu = tanhf(mua[a] + sbmu[a]);
    const float dd = tanhf(dva[a] + sbLd[a]);
    const float ld = expf(dd);     // L diagonal; P_aa = ld^2; Lc_aa = 1/ld
    const float am = actn - mu;
    adv = fmaf(am * am, ld * ld, adv);
    const uint32_t e = (uint32_t)row * AD + (uint32_t)a;
    uint32_t x0 = 0u;
    uint32_t x1 = e;
    tf2x32_key42(x0, x1);
    const float z = jax_normal_from_bits(x0 ^ x1);
    float s = fmaf(z, 1.0f / ld, mu);
    s = fminf(fmaxf(s, -1.0f), 1.0f) * rl_mask;
    smp[a] = s;
  }
  const float q = fmaf(-0.5f, adv, vacc);

  float4* so = reinterpret_cast<float4*>(out) + (size_t)row * 2;
  so[0] = make_float4(smp[0], smp[1], smp[2], smp[3]);
  so[1] = make_float4(smp[4], smp[5], smp[6], smp[7]);
  out[(size_t)N * AD + row] = q;                  // Q
  out[(size_t)N * AD + (size_t)N + row] = vacc;   // value
}

extern "C" void kernel_launch(void* const* d_in, const int* in_sizes, int n_in,
                              void* d_out, int out_size, void* d_ws, size_t ws_size,
                              hipStream_t stream) {
  const float* X   = (const float*)d_in[0];
  const float* RL  = (const float*)d_in[1];
  const float* act = (const float*)d_in[2];
  const float* W1  = (const float*)d_in[3];
  const float* b1  = (const float*)d_in[4];
  const float* W2  = (const float*)d_in[5];
  const float* b2  = (const float*)d_in[6];
  const float* Wv  = (const float*)d_in[7];
  const float* bv  = (const float*)d_in[8];
  const float* Wmu = (const float*)d_in[9];
  const float* bmu = (const float*)d_in[10];
  const float* WL  = (const float*)d_in[11];
  const float* bL  = (const float*)d_in[12];
  const int N = in_sizes[1];  // RL_indice length
  const int blocks = (N + RPB - 1) / RPB;
  hipLaunchKernelGGL(naf_fused, dim3(blocks), dim3(TPB), 0, stream,
                     X, RL, act, W1, b1, W2, b2, Wv, bv, Wmu, bmu, WL, bL,
                     (float*)d_out, N);
}